// Round 4
// baseline (253.379 us; speedup 1.0000x reference)
//
#include <hip/hip_runtime.h>

// EMA along T for x[B=8, T=4096, F=1024] fp32.
// y_t = a*y_{t-1} + (1-a)*x_t, a=0.9, y_{-1}=0.
//
// Chunked scan with truncated warm-up (W=64; 0.9^64 ~ 1.2e-3 << 2.58e-2
// threshold). Thread = (b, f4, chunk); wave = 64 contiguous f4 -> 1 KiB/load.
//
// v5: single-variable A/B vs v2 (98 us): nontemporal store -> REGULAR store.
// Evidence trail: v1 (more waves), v3 (deep reg prefetch), v4 (contiguous
// block streams) were ALL null; per-CU rate pinned at ~15 GB/s. The one
// thing every version shared: __builtin_nontemporal_store. Theory: nt
// stores bypass L2 and retire only at the HBM write path; they share vmcnt
// with loads, so write backpressure serializes the read pipeline (explains
// why prefetch depth and wave count didn't matter), and the fine-grained
// read/write interleave at the DRAM bus costs turnaround (2.6/6.3 = 41% of
// copy efficiency). Regular stores retire at L2 (fast vmcnt release) and
// L2 write-back batches the write stream for the memory controller.

using f4 = __attribute__((ext_vector_type(4))) float;

constexpr int Bn = 8;
constexpr int Tn = 4096;
constexpr int F4 = 256;        // 1024 floats / 4
constexpr int L  = 64;         // outputs per thread
constexpr int W  = 64;         // warm-up steps (0.9^64 ~ 1.18e-3)
constexpr float A   = 0.9f;
constexpr float OMA = 0.1f;    // 1 - alpha

__global__ __launch_bounds__(256) void ema_kernel(const f4* __restrict__ x,
                                                  f4* __restrict__ y) {
    const int tid          = threadIdx.x;
    const int lane_f       = tid & 63;        // f4 within group (wave-contig)
    const int chunk_in_blk = tid >> 6;        // 0..3 (wave-uniform)

    // XCD pinning: all 16 chunk-blocks of a stream p=(b,fg) share one XCD so
    // warm-up reads hit the L2 the previous chunk's main reads stream through.
    const int blk      = blockIdx.x;          // 0..511
    const int xcd      = blk & 7;
    const int slot     = blk >> 3;            // 0..63
    const int chunkgrp = slot & 15;           // 0..15
    const int p        = ((slot >> 4) << 3) | xcd;   // stream id 0..31
    const int fg       = p & 3;               // 4 f-groups
    const int b        = p >> 2;              // 8 batches

    const int chunk = chunkgrp * 4 + chunk_in_blk;   // 0..63
    const int f4i   = (fg << 6) + lane_f;            // 0..255
    const int t0    = chunk * L;

    const f4* __restrict__ xp = x + (size_t)b * Tn * F4 + f4i;
    f4*       __restrict__ yp = y + (size_t)b * Tn * F4 + f4i;

    float ax = 0.f, ay = 0.f, az = 0.f, aw = 0.f;

    if (chunk > 0) {   // wave-uniform branch
        int idx = (t0 - W) * F4;
        #pragma unroll 8
        for (int i = 0; i < W; ++i) {
            f4 v = xp[idx];
            idx += F4;
            ax = fmaf(A, ax, OMA * v.x);
            ay = fmaf(A, ay, OMA * v.y);
            az = fmaf(A, az, OMA * v.z);
            aw = fmaf(A, aw, OMA * v.w);
        }
    }

    int idx = t0 * F4;
    #pragma unroll 8
    for (int i = 0; i < L; ++i) {
        f4 v = xp[idx];
        ax = fmaf(A, ax, OMA * v.x);
        ay = fmaf(A, ay, OMA * v.y);
        az = fmaf(A, az, OMA * v.z);
        aw = fmaf(A, aw, OMA * v.w);
        f4 o;
        o.x = ax; o.y = ay; o.z = az; o.w = aw;
        yp[idx] = o;                 // regular write-back store (the A/B)
        idx += F4;
    }
}

extern "C" void kernel_launch(void* const* d_in, const int* in_sizes, int n_in,
                              void* d_out, int out_size, void* d_ws, size_t ws_size,
                              hipStream_t stream) {
    const f4* x = (const f4*)d_in[0];
    f4*       y = (f4*)d_out;
    dim3 grid(Bn * 4 * 16);  // 512 blocks (8 b x 4 fg x 16 chunkgroups)
    dim3 block(256);
    ema_kernel<<<grid, block, 0, stream>>>(x, y);
}

// Round 5
// 248.040 us; speedup vs baseline: 1.0215x; 1.0215x over previous
//
#include <hip/hip_runtime.h>

// EMA along T for x[B=8, T=4096, F=1024] fp32.
// y_t = a*y_{t-1} + (1-a)*x_t, a=0.9, y_{-1}=0.
//
// Chunked scan with truncated warm-up (W=64; 0.9^64 ~ 1.2e-3 << 2.58e-2).
//
// v6: FORCED load double-buffering. Post-mortem trail:
//   v1 waves 4->8/CU: null. v3 source-level prefetch: compiler sank the
//   loads (VGPR stayed 36) -- never actually tested MLP. v4 contiguous
//   block streams: worse. v5 regular-vs-nt store: byte-identical counters.
// All variants shared a structural flaw: the unrolled loop issues stores
// OLDER than the next loads' consume point, so every unroll block's
// s_waitcnt drains all prior stores -> effective read MLP ~1-2 loads/wave.
// v6 fixes the ordering (consume phase waits at vmcnt(16): 8 newer loads +
// 8 newer stores outstanding, stores never gate) and pins the schedule
// with __builtin_amdgcn_sched_barrier(0) fences so the compiler cannot
// sink loads into the consume phase (the v3 failure mode).
// Geometry: 1024 single-wave blocks (64 thr), L=128 (amp 1.5 -- minimal
// L1 traffic that still fills all 256 CUs, 4 waves/CU), XCD-pinned
// streams. Verification that the experiment ran: VGPR must jump to ~100.

using f4 = __attribute__((ext_vector_type(4))) float;

constexpr int Bn = 8;
constexpr int Tn = 4096;
constexpr int F4 = 256;        // 1024 floats / 4
constexpr int L  = 128;        // outputs per thread (32 chunks)
constexpr int W  = 64;         // warm-up steps (0.9^64 ~ 1.18e-3)
constexpr int PB = 8;          // load-block size (8 KiB/wave in flight/buffer)
constexpr float A   = 0.9f;
constexpr float OMA = 0.1f;    // 1 - alpha

template <int NSKIP, int NSTORE>
__device__ __forceinline__ void ema_stream(const f4* __restrict__ xs,
                                           f4* __restrict__ ys,
                                           float& ax, float& ay,
                                           float& az, float& aw) {
    constexpr int N  = NSKIP + NSTORE;   // 192 or 128
    constexpr int NB = N / PB;           // 24 or 16 (even)
    static_assert(N % PB == 0 && NB % 2 == 0, "geometry");
    f4 bufA[PB], bufB[PB];

    // prologue: block 0 -> A
    #pragma unroll
    for (int i = 0; i < PB; ++i) bufA[i] = xs[(size_t)i * F4];
    __builtin_amdgcn_sched_barrier(0);

    #pragma unroll
    for (int kb = 0; kb < NB; kb += 2) {
        // issue loads for block kb+1 -> B (newer than A's data)
        if (kb + 1 < NB) {
            #pragma unroll
            for (int i = 0; i < PB; ++i)
                bufB[i] = xs[(size_t)((kb + 1) * PB + i) * F4];
        }
        __builtin_amdgcn_sched_barrier(0);
        // consume A = block kb (waits vmcnt<=8: B's loads; stores all newer)
        #pragma unroll
        for (int i = 0; i < PB; ++i) {
            const int t = kb * PB + i;           // compile-time
            f4 v = bufA[i];
            ax = fmaf(A, ax, OMA * v.x);
            ay = fmaf(A, ay, OMA * v.y);
            az = fmaf(A, az, OMA * v.z);
            aw = fmaf(A, aw, OMA * v.w);
            if (t >= NSKIP) {
                f4 o;
                o.x = ax; o.y = ay; o.z = az; o.w = aw;
                __builtin_nontemporal_store(o, ys + (size_t)(t - NSKIP) * F4);
            }
        }
        __builtin_amdgcn_sched_barrier(0);
        // issue loads for block kb+2 -> A
        if (kb + 2 < NB) {
            #pragma unroll
            for (int i = 0; i < PB; ++i)
                bufA[i] = xs[(size_t)((kb + 2) * PB + i) * F4];
        }
        __builtin_amdgcn_sched_barrier(0);
        // consume B = block kb+1
        if (kb + 1 < NB) {
            #pragma unroll
            for (int i = 0; i < PB; ++i) {
                const int t = (kb + 1) * PB + i; // compile-time
                f4 v = bufB[i];
                ax = fmaf(A, ax, OMA * v.x);
                ay = fmaf(A, ay, OMA * v.y);
                az = fmaf(A, az, OMA * v.z);
                aw = fmaf(A, aw, OMA * v.w);
                if (t >= NSKIP) {
                    f4 o;
                    o.x = ax; o.y = ay; o.z = az; o.w = aw;
                    __builtin_nontemporal_store(o, ys + (size_t)(t - NSKIP) * F4);
                }
            }
        }
        __builtin_amdgcn_sched_barrier(0);
    }
}

__global__ __launch_bounds__(64) void ema_kernel(const f4* __restrict__ x,
                                                 f4* __restrict__ y) {
    // 1024 single-wave blocks = 8 xcd x 32 chunk x 4 phi; stream p=(b,fg)
    // pinned to XCD p&7 so warm-up re-reads hit the same L2 the previous
    // chunk's main reads went through.
    const int lane  = threadIdx.x;     // 0..63
    const int blk   = blockIdx.x;      // 0..1023
    const int xcd   = blk & 7;
    const int slot  = blk >> 3;        // 0..127
    const int chunk = slot & 31;       // 0..31 (wave-uniform)
    const int phi   = slot >> 5;       // 0..3
    const int p     = (phi << 3) | xcd;  // stream 0..31
    const int fg    = p & 3;
    const int b     = p >> 2;

    const int f4i = (fg << 6) | lane;  // 0..255: wave = 1 KiB contiguous
    const int t0  = chunk * L;

    const f4* __restrict__ xp = x + (size_t)b * Tn * F4 + f4i;
    f4*       __restrict__ yp = y + (size_t)b * Tn * F4 + f4i;

    float ax = 0.f, ay = 0.f, az = 0.f, aw = 0.f;
    f4* __restrict__ op = yp + (size_t)t0 * F4;

    if (chunk > 0) {   // wave-uniform branch
        ema_stream<W, L>(xp + (size_t)(t0 - W) * F4, op, ax, ay, az, aw);
    } else {
        ema_stream<0, L>(xp, op, ax, ay, az, aw);
    }
}

extern "C" void kernel_launch(void* const* d_in, const int* in_sizes, int n_in,
                              void* d_out, int out_size, void* d_ws, size_t ws_size,
                              hipStream_t stream) {
    const f4* x = (const f4*)d_in[0];
    f4*       y = (f4*)d_out;
    dim3 grid(Bn * (Tn / L) * 4);  // 1024 blocks
    dim3 block(64);
    ema_kernel<<<grid, block, 0, stream>>>(x, y);
}